// Round 3
// baseline (274.062 us; speedup 1.0000x reference)
//
#include <hip/hip_runtime.h>

#define NROWS   262144
#define DIN     480
#define DOUT    480

#define M_TILE  32
#define XSTR    360   // ushort stride; 720B/row -> bank-shift 20 (conflict-free b128 pattern)

#define CST_SILU 1.6765290f
#define CST_RELU 1.4142135623730951f
#define INV_S128 0.08838834764831845f
#define INV_S64  0.125f
#define INV_S32  0.17677669529663687f

// ws fragment layout (bf16x8 per lane, 1024B per fragment):
//   W0 tile t(0..13) kk(0..3) -> t*4+kk (0..55); W1 vu,kk -> 56+vu*2+kk; W2 tu -> 64+tu
#define WS_FRAGS 66
#define WS_BYTES (WS_FRAGS * 64 * 16)

typedef short bf16x8 __attribute__((ext_vector_type(8)));
typedef short s16x4  __attribute__((ext_vector_type(4)));
typedef float f32x4  __attribute__((ext_vector_type(4)));

__device__ __forceinline__ ushort f2bf(float f) {
    unsigned u = __float_as_uint(f);
    u = (u + 0x7FFFu + ((u >> 16) & 1u)) >> 16;   // RNE
    return (ushort)u;
}

__device__ __forceinline__ bf16x8 load_b_frag(const float* __restrict__ W, int ldw,
                                              int kbase, int nbase, int lane) {
    int n  = nbase + (lane & 15);
    int k0 = kbase + ((lane >> 4) << 3);
    bf16x8 f;
#pragma unroll
    for (int e = 0; e < 8; ++e) f[e] = (short)f2bf(W[(k0 + e) * ldw + n]);
    return f;
}

__global__ __launch_bounds__(64) void prep_frags(
        const float* __restrict__ W0, const float* __restrict__ W1,
        const float* __restrict__ W2, ushort* __restrict__ ws) {
    const int b = blockIdx.x, lane = threadIdx.x;
    const int lr = lane & 15, kg = lane >> 4;
    const float* W; int ldw, n, k0;
    if (b < 56)      { W = W0; ldw = 224; n = (b >> 2) * 16 + lr; k0 = (b & 3) * 32 + (kg << 3); }
    else if (b < 64) { int t = b - 56; W = W1; ldw = 64; n = (t >> 1) * 16 + lr; k0 = (t & 1) * 32 + (kg << 3); }
    else             { W = W2; ldw = 32; n = (b - 64) * 16 + lr; k0 = (kg << 3); }
    bf16x8 f;
#pragma unroll
    for (int e = 0; e < 8; ++e) f[e] = (short)f2bf(W[(k0 + e) * ldw + n]);
    *reinterpret_cast<bf16x8*>(ws + (b * 64 + lane) * 8) = f;
}

template <bool PRE>
__global__ __launch_bounds__(256, 6) void percep_kernel(
        const float* __restrict__ x,  const float* __restrict__ W0,
        const float* __restrict__ bias0, const float* __restrict__ W1,
        const float* __restrict__ W2, float* __restrict__ out,
        const ushort* __restrict__ ws) {
    __shared__ __align__(16) ushort xs[M_TILE * XSTR];   // 23040 B -> 6 blocks/CU

    const int tid  = threadIdx.x;
    const int lane = tid & 63;
    const int wid  = tid >> 6;
    const int lr   = lane & 15;
    const int kg   = lane >> 4;
    const int row0 = blockIdx.x * M_TILE;
    const bf16x8* F = reinterpret_cast<const bf16x8*>(ws);

    // ---------- stage x1/x2 -> LDS bf16, deinterleaved; compile-time index math ----------
    // x1[n,i,m] = x[n,128+3i+m] -> xs col 64m + i ; x2[n,i,m] = x[n,320+5i+m] -> 192 + 32m + i
#pragma unroll
    for (int it = 0; it < 2; ++it) {
        int idx = tid + it * 256;
        int row = idx >> 4, g = idx & 15;
        const float4* p = reinterpret_cast<const float4*>(x + (row0 + row) * DIN + 128 + 12 * g);
        float4 q0 = p[0], q1 = p[1], q2 = p[2];
        float v[12] = { q0.x, q0.y, q0.z, q0.w, q1.x, q1.y, q1.z, q1.w, q2.x, q2.y, q2.z, q2.w };
#pragma unroll
        for (int m = 0; m < 3; ++m) {
            s16x4 o = { (short)f2bf(v[m]), (short)f2bf(v[m + 3]),
                        (short)f2bf(v[m + 6]), (short)f2bf(v[m + 9]) };
            *reinterpret_cast<s16x4*>(&xs[row * XSTR + 64 * m + 4 * g]) = o;
        }
    }
    {
        int row = tid >> 3, g = tid & 7;
        const float4* p = reinterpret_cast<const float4*>(x + (row0 + row) * DIN + 320 + 20 * g);
        float4 q0 = p[0], q1 = p[1], q2 = p[2], q3 = p[3], q4 = p[4];
        float v[20] = { q0.x, q0.y, q0.z, q0.w, q1.x, q1.y, q1.z, q1.w, q2.x, q2.y, q2.z, q2.w,
                        q3.x, q3.y, q3.z, q3.w, q4.x, q4.y, q4.z, q4.w };
#pragma unroll
        for (int m = 0; m < 5; ++m) {
            s16x4 o = { (short)f2bf(v[m]), (short)f2bf(v[m + 5]),
                        (short)f2bf(v[m + 10]), (short)f2bf(v[m + 15]) };
            *reinterpret_cast<s16x4*>(&xs[row * XSTR + 192 + 32 * m + 4 * g]) = o;
        }
    }

    // ---------- x0 A-frags direct global -> registers (no LDS round-trip) ----------
    bf16x8 aS[2][4];
#pragma unroll
    for (int rf = 0; rf < 2; ++rf)
#pragma unroll
        for (int kk = 0; kk < 4; ++kk) {
            const float4* p = reinterpret_cast<const float4*>(
                x + (row0 + rf * 16 + lr) * DIN + kk * 32 + (kg << 3));
            float4 u0 = p[0], u1 = p[1];
            bf16x8 a = { (short)f2bf(u0.x), (short)f2bf(u0.y), (short)f2bf(u0.z), (short)f2bf(u0.w),
                         (short)f2bf(u1.x), (short)f2bf(u1.y), (short)f2bf(u1.z), (short)f2bf(u1.w) };
            aS[rf][kk] = a;
        }

    // ---------- S phase: gate tiles -> registers (lane-matched to V/T), silu -> out ----------
    f32x4 gV[2], gT[2];

    auto gate_tile = [&](int st, f32x4* g) {
        bf16x8 b[4];
#pragma unroll
        for (int kk = 0; kk < 4; ++kk)
            b[kk] = PRE ? F[(st * 4 + kk) * 64 + lane]
                        : load_b_frag(W0, 224, kk * 32, st * 16, lane);
        float bias = bias0[st * 16 + lr];
#pragma unroll
        for (int rf = 0; rf < 2; ++rf) {
            f32x4 acc = { 0.f, 0.f, 0.f, 0.f };
#pragma unroll
            for (int kk = 0; kk < 4; ++kk)
                acc = __builtin_amdgcn_mfma_f32_16x16x32_bf16(aS[rf][kk], b[kk], acc, 0, 0, 0);
#pragma unroll
            for (int r = 0; r < 4; ++r) {
                float s = acc[r] * INV_S128 + bias;
                g[rf][r] = fmaxf(s, 0.f) * CST_RELU;
            }
        }
    };
    auto silu_tile = [&](int st) {
        bf16x8 b[4];
#pragma unroll
        for (int kk = 0; kk < 4; ++kk)
            b[kk] = PRE ? F[(st * 4 + kk) * 64 + lane]
                        : load_b_frag(W0, 224, kk * 32, st * 16, lane);
        float bias = bias0[st * 16 + lr];
#pragma unroll
        for (int rf = 0; rf < 2; ++rf) {
            f32x4 acc = { 0.f, 0.f, 0.f, 0.f };
#pragma unroll
            for (int kk = 0; kk < 4; ++kk)
                acc = __builtin_amdgcn_mfma_f32_16x16x32_bf16(aS[rf][kk], b[kk], acc, 0, 0, 0);
#pragma unroll
            for (int r = 0; r < 4; ++r) {
                float s = acc[r] * INV_S128 + bias;
                float val = CST_SILU * s * __builtin_amdgcn_rcpf(1.f + __expf(-s));
                out[(row0 + rf * 16 + (kg << 2) + r) * DOUT + st * 16 + lr] = val;
            }
        }
    };

    // wave vu computes gate tile 8+vu (feeds its own V) and 12+tu (feeds its own T)
    if      (wid == 0) { gate_tile(8,  gV); gate_tile(12, gT); silu_tile(0); }
    else if (wid == 1) { gate_tile(9,  gV); gate_tile(13, gT); silu_tile(1); }
    else if (wid == 2) { gate_tile(10, gV); silu_tile(2); silu_tile(3); silu_tile(4); }
    else               { gate_tile(11, gV); silu_tile(5); silu_tile(6); silu_tile(7); }

    __syncthreads();   // staging complete (only barrier in the kernel)

    // ---------- V: 3x (32x64)@(64x64); gate = own register ----------
    {
        const int vu = wid;
        bf16x8 bv0 = PRE ? F[(56 + vu * 2) * 64 + lane]     : load_b_frag(W1, 64, 0,  vu * 16, lane);
        bf16x8 bv1 = PRE ? F[(56 + vu * 2 + 1) * 64 + lane] : load_b_frag(W1, 64, 32, vu * 16, lane);
        const int j = vu * 16 + lr;
#pragma unroll
        for (int rf = 0; rf < 2; ++rf) {
            const ushort* base = &xs[(rf * 16 + lr) * XSTR + (kg << 3)];
            f32x4 a0 = {0,0,0,0}, a1 = {0,0,0,0}, a2 = {0,0,0,0};
            a0 = __builtin_amdgcn_mfma_f32_16x16x32_bf16(*reinterpret_cast<const bf16x8*>(base +   0), bv0, a0, 0, 0, 0);
            a0 = __builtin_amdgcn_mfma_f32_16x16x32_bf16(*reinterpret_cast<const bf16x8*>(base +  32), bv1, a0, 0, 0, 0);
            a1 = __builtin_amdgcn_mfma_f32_16x16x32_bf16(*reinterpret_cast<const bf16x8*>(base +  64), bv0, a1, 0, 0, 0);
            a1 = __builtin_amdgcn_mfma_f32_16x16x32_bf16(*reinterpret_cast<const bf16x8*>(base +  96), bv1, a1, 0, 0, 0);
            a2 = __builtin_amdgcn_mfma_f32_16x16x32_bf16(*reinterpret_cast<const bf16x8*>(base + 128), bv0, a2, 0, 0, 0);
            a2 = __builtin_amdgcn_mfma_f32_16x16x32_bf16(*reinterpret_cast<const bf16x8*>(base + 160), bv1, a2, 0, 0, 0);
#pragma unroll
            for (int r = 0; r < 4; ++r) {
                int row = rf * 16 + (kg << 2) + r;
                float g = gV[rf][r] * INV_S64;
                float* po = out + (row0 + row) * DOUT + 128 + 3 * j;
                po[0] = a0[r] * g; po[1] = a1[r] * g; po[2] = a2[r] * g;
            }
        }
    }

    // ---------- T: 5x (32x32)@(32x32) on waves 0/1; gate = own register ----------
    if (wid < 2) {
        bf16x8 bt = PRE ? F[(64 + wid) * 64 + lane] : load_b_frag(W2, 32, 0, wid * 16, lane);
        const int j = wid * 16 + lr;
#pragma unroll
        for (int rf = 0; rf < 2; ++rf) {
            const ushort* base = &xs[(rf * 16 + lr) * XSTR + 192 + (kg << 3)];
            f32x4 z = {0,0,0,0};
            f32x4 a0 = __builtin_amdgcn_mfma_f32_16x16x32_bf16(*reinterpret_cast<const bf16x8*>(base +   0), bt, z, 0, 0, 0);
            f32x4 a1 = __builtin_amdgcn_mfma_f32_16x16x32_bf16(*reinterpret_cast<const bf16x8*>(base +  32), bt, z, 0, 0, 0);
            f32x4 a2 = __builtin_amdgcn_mfma_f32_16x16x32_bf16(*reinterpret_cast<const bf16x8*>(base +  64), bt, z, 0, 0, 0);
            f32x4 a3 = __builtin_amdgcn_mfma_f32_16x16x32_bf16(*reinterpret_cast<const bf16x8*>(base +  96), bt, z, 0, 0, 0);
            f32x4 a4 = __builtin_amdgcn_mfma_f32_16x16x32_bf16(*reinterpret_cast<const bf16x8*>(base + 128), bt, z, 0, 0, 0);
#pragma unroll
            for (int r = 0; r < 4; ++r) {
                int row = rf * 16 + (kg << 2) + r;
                float g = gT[rf][r] * INV_S32;
                float* po = out + (row0 + row) * DOUT + 320 + 5 * j;
                po[0] = a0[r] * g; po[1] = a1[r] * g; po[2] = a2[r] * g;
                po[3] = a3[r] * g; po[4] = a4[r] * g;
            }
        }
    }
}

extern "C" void kernel_launch(void* const* d_in, const int* in_sizes, int n_in,
                              void* d_out, int out_size, void* d_ws, size_t ws_size,
                              hipStream_t stream) {
    const float* x  = (const float*)d_in[0];
    const float* W0 = (const float*)d_in[1];
    const float* b0 = (const float*)d_in[2];
    const float* W1 = (const float*)d_in[3];
    const float* W2 = (const float*)d_in[4];
    float* out = (float*)d_out;
    dim3 grid(NROWS / M_TILE), block(256);
    if (ws_size >= WS_BYTES) {
        hipLaunchKernelGGL(prep_frags, dim3(WS_FRAGS), dim3(64), 0, stream, W0, W1, W2, (ushort*)d_ws);
        hipLaunchKernelGGL((percep_kernel<true>), grid, block, 0, stream,
                           x, W0, b0, W1, W2, out, (const ushort*)d_ws);
    } else {
        hipLaunchKernelGGL((percep_kernel<false>), grid, block, 0, stream,
                           x, W0, b0, W1, W2, out, (const ushort*)d_ws);
    }
}

// Round 4
// 248.811 us; speedup vs baseline: 1.1015x; 1.1015x over previous
//
#include <hip/hip_runtime.h>

#define NROWS   262144
#define DIN     480
#define DOUT    480

#define M_TILE  32
#define XSTR    360   // ushort stride for staged x1/x2 regions

#define CST_SILU 1.6765290f
#define CST_RELU 1.4142135623730951f
#define INV_S128 0.08838834764831845f
#define INV_S64  0.125f
#define INV_S32  0.17677669529663687f

// ws fragment layout (bf16x8 per lane, 1024B per fragment):
//   W0 tile t(0..13) kk(0..3) -> t*4+kk (0..55); W1 vu,kk -> 56+vu*2+kk; W2 tu -> 64+tu
#define WS_FRAGS 66
#define WS_BYTES (WS_FRAGS * 64 * 16)

typedef short bf16x8 __attribute__((ext_vector_type(8)));
typedef short s16x4  __attribute__((ext_vector_type(4)));
typedef float f32x4  __attribute__((ext_vector_type(4)));

__device__ __forceinline__ ushort f2bf(float f) {
    unsigned u = __float_as_uint(f);
    u = (u + 0x7FFFu + ((u >> 16) & 1u)) >> 16;   // RNE
    return (ushort)u;
}

__device__ __forceinline__ bf16x8 load_b_frag(const float* __restrict__ W, int ldw,
                                              int kbase, int nbase, int lane) {
    int n  = nbase + (lane & 15);
    int k0 = kbase + ((lane >> 4) << 3);
    bf16x8 f;
#pragma unroll
    for (int e = 0; e < 8; ++e) f[e] = (short)f2bf(W[(k0 + e) * ldw + n]);
    return f;
}

__global__ __launch_bounds__(64) void prep_frags(
        const float* __restrict__ W0, const float* __restrict__ W1,
        const float* __restrict__ W2, ushort* __restrict__ ws) {
    const int b = blockIdx.x, lane = threadIdx.x;
    const int lr = lane & 15, kg = lane >> 4;
    const float* W; int ldw, n, k0;
    if (b < 56)      { W = W0; ldw = 224; n = (b >> 2) * 16 + lr; k0 = (b & 3) * 32 + (kg << 3); }
    else if (b < 64) { int t = b - 56; W = W1; ldw = 64; n = (t >> 1) * 16 + lr; k0 = (t & 1) * 32 + (kg << 3); }
    else             { W = W2; ldw = 32; n = (b - 64) * 16 + lr; k0 = (kg << 3); }
    bf16x8 f;
#pragma unroll
    for (int e = 0; e < 8; ++e) f[e] = (short)f2bf(W[(k0 + e) * ldw + n]);
    *reinterpret_cast<bf16x8*>(ws + (b * 64 + lane) * 8) = f;
}

template <bool PRE>
__global__ __launch_bounds__(256, 4) void percep_kernel(   // 4, NOT 6: round-3's 6 forced VGPR=40 -> spills (+68MB writes)
        const float* __restrict__ x,  const float* __restrict__ W0,
        const float* __restrict__ bias0, const float* __restrict__ W1,
        const float* __restrict__ W2, float* __restrict__ out,
        const ushort* __restrict__ ws) {
    __shared__ __align__(16) ushort xs[M_TILE * XSTR];   // 23040 B

    const int tid  = threadIdx.x;
    const int lane = tid & 63;
    const int wid  = tid >> 6;
    const int lr   = lane & 15;
    const int kg   = lane >> 4;
    const int row0 = blockIdx.x * M_TILE;
    const bf16x8* F = reinterpret_cast<const bf16x8*>(ws);

    // ---------- stage x1/x2 -> LDS bf16, deinterleaved; compile-time index math ----------
    // x1[n,i,m] = x[n,128+3i+m] -> xs col 64m + i ; x2[n,i,m] = x[n,320+5i+m] -> 192 + 32m + i
#pragma unroll
    for (int it = 0; it < 2; ++it) {
        int idx = tid + it * 256;
        int row = idx >> 4, g = idx & 15;
        const float4* p = reinterpret_cast<const float4*>(x + (row0 + row) * DIN + 128 + 12 * g);
        float4 q0 = p[0], q1 = p[1], q2 = p[2];
        float v[12] = { q0.x, q0.y, q0.z, q0.w, q1.x, q1.y, q1.z, q1.w, q2.x, q2.y, q2.z, q2.w };
#pragma unroll
        for (int m = 0; m < 3; ++m) {
            s16x4 o = { (short)f2bf(v[m]), (short)f2bf(v[m + 3]),
                        (short)f2bf(v[m + 6]), (short)f2bf(v[m + 9]) };
            *reinterpret_cast<s16x4*>(&xs[row * XSTR + 64 * m + 4 * g]) = o;
        }
    }
    {
        int row = tid >> 3, g = tid & 7;
        const float4* p = reinterpret_cast<const float4*>(x + (row0 + row) * DIN + 320 + 20 * g);
        float4 q0 = p[0], q1 = p[1], q2 = p[2], q3 = p[3], q4 = p[4];
        float v[20] = { q0.x, q0.y, q0.z, q0.w, q1.x, q1.y, q1.z, q1.w, q2.x, q2.y, q2.z, q2.w,
                        q3.x, q3.y, q3.z, q3.w, q4.x, q4.y, q4.z, q4.w };
#pragma unroll
        for (int m = 0; m < 5; ++m) {
            s16x4 o = { (short)f2bf(v[m]), (short)f2bf(v[m + 5]),
                        (short)f2bf(v[m + 10]), (short)f2bf(v[m + 15]) };
            *reinterpret_cast<s16x4*>(&xs[row * XSTR + 192 + 32 * m + 4 * g]) = o;
        }
    }

    // ---------- x0 A-frags direct global -> registers (no LDS round-trip) ----------
    bf16x8 aS[2][4];
#pragma unroll
    for (int rf = 0; rf < 2; ++rf)
#pragma unroll
        for (int kk = 0; kk < 4; ++kk) {
            const float4* p = reinterpret_cast<const float4*>(
                x + (row0 + rf * 16 + lr) * DIN + kk * 32 + (kg << 3));
            float4 u0 = p[0], u1 = p[1];
            bf16x8 a = { (short)f2bf(u0.x), (short)f2bf(u0.y), (short)f2bf(u0.z), (short)f2bf(u0.w),
                         (short)f2bf(u1.x), (short)f2bf(u1.y), (short)f2bf(u1.z), (short)f2bf(u1.w) };
            aS[rf][kk] = a;
        }

    // ---------- S phase: gate tiles -> registers (lane-matched to V/T), silu -> out ----------
    f32x4 gV[2], gT[2];

    auto gate_tile = [&](int st, f32x4* g) {
        bf16x8 b[4];
#pragma unroll
        for (int kk = 0; kk < 4; ++kk)
            b[kk] = PRE ? F[(st * 4 + kk) * 64 + lane]
                        : load_b_frag(W0, 224, kk * 32, st * 16, lane);
        float bias = bias0[st * 16 + lr];
#pragma unroll
        for (int rf = 0; rf < 2; ++rf) {
            f32x4 acc = { 0.f, 0.f, 0.f, 0.f };
#pragma unroll
            for (int kk = 0; kk < 4; ++kk)
                acc = __builtin_amdgcn_mfma_f32_16x16x32_bf16(aS[rf][kk], b[kk], acc, 0, 0, 0);
#pragma unroll
            for (int r = 0; r < 4; ++r) {
                float s = acc[r] * INV_S128 + bias;
                g[rf][r] = fmaxf(s, 0.f) * CST_RELU;
            }
        }
    };
    auto silu_tile = [&](int st) {
        bf16x8 b[4];
#pragma unroll
        for (int kk = 0; kk < 4; ++kk)
            b[kk] = PRE ? F[(st * 4 + kk) * 64 + lane]
                        : load_b_frag(W0, 224, kk * 32, st * 16, lane);
        float bias = bias0[st * 16 + lr];
#pragma unroll
        for (int rf = 0; rf < 2; ++rf) {
            f32x4 acc = { 0.f, 0.f, 0.f, 0.f };
#pragma unroll
            for (int kk = 0; kk < 4; ++kk)
                acc = __builtin_amdgcn_mfma_f32_16x16x32_bf16(aS[rf][kk], b[kk], acc, 0, 0, 0);
#pragma unroll
            for (int r = 0; r < 4; ++r) {
                float s = acc[r] * INV_S128 + bias;
                float val = CST_SILU * s * __builtin_amdgcn_rcpf(1.f + __expf(-s));
                out[(row0 + rf * 16 + (kg << 2) + r) * DOUT + st * 16 + lr] = val;
            }
        }
    };

    // wave vu computes gate tile 8+vu (feeds its own V) and 12+tu (feeds its own T)
    if      (wid == 0) { gate_tile(8,  gV); gate_tile(12, gT); silu_tile(0); }
    else if (wid == 1) { gate_tile(9,  gV); gate_tile(13, gT); silu_tile(1); }
    else if (wid == 2) { gate_tile(10, gV); silu_tile(2); silu_tile(3); silu_tile(4); }
    else               { gate_tile(11, gV); silu_tile(5); silu_tile(6); silu_tile(7); }

    __syncthreads();   // staging complete (only barrier in the kernel)

    // ---------- V: 3x (32x64)@(64x64); gate = own register ----------
    {
        const int vu = wid;
        bf16x8 bv0 = PRE ? F[(56 + vu * 2) * 64 + lane]     : load_b_frag(W1, 64, 0,  vu * 16, lane);
        bf16x8 bv1 = PRE ? F[(56 + vu * 2 + 1) * 64 + lane] : load_b_frag(W1, 64, 32, vu * 16, lane);
        const int j = vu * 16 + lr;
#pragma unroll
        for (int rf = 0; rf < 2; ++rf) {
            const ushort* base = &xs[(rf * 16 + lr) * XSTR + (kg << 3)];
            f32x4 a0 = {0,0,0,0}, a1 = {0,0,0,0}, a2 = {0,0,0,0};
            a0 = __builtin_amdgcn_mfma_f32_16x16x32_bf16(*reinterpret_cast<const bf16x8*>(base +   0), bv0, a0, 0, 0, 0);
            a0 = __builtin_amdgcn_mfma_f32_16x16x32_bf16(*reinterpret_cast<const bf16x8*>(base +  32), bv1, a0, 0, 0, 0);
            a1 = __builtin_amdgcn_mfma_f32_16x16x32_bf16(*reinterpret_cast<const bf16x8*>(base +  64), bv0, a1, 0, 0, 0);
            a1 = __builtin_amdgcn_mfma_f32_16x16x32_bf16(*reinterpret_cast<const bf16x8*>(base +  96), bv1, a1, 0, 0, 0);
            a2 = __builtin_amdgcn_mfma_f32_16x16x32_bf16(*reinterpret_cast<const bf16x8*>(base + 128), bv0, a2, 0, 0, 0);
            a2 = __builtin_amdgcn_mfma_f32_16x16x32_bf16(*reinterpret_cast<const bf16x8*>(base + 160), bv1, a2, 0, 0, 0);
#pragma unroll
            for (int r = 0; r < 4; ++r) {
                int row = rf * 16 + (kg << 2) + r;
                float g = gV[rf][r] * INV_S64;
                float* po = out + (row0 + row) * DOUT + 128 + 3 * j;
                po[0] = a0[r] * g; po[1] = a1[r] * g; po[2] = a2[r] * g;
            }
        }
    }

    // ---------- T: 5x (32x32)@(32x32) on waves 0/1; gate = own register ----------
    if (wid < 2) {
        bf16x8 bt = PRE ? F[(64 + wid) * 64 + lane] : load_b_frag(W2, 32, 0, wid * 16, lane);
        const int j = wid * 16 + lr;
#pragma unroll
        for (int rf = 0; rf < 2; ++rf) {
            const ushort* base = &xs[(rf * 16 + lr) * XSTR + 192 + (kg << 3)];
            f32x4 z = {0,0,0,0};
            f32x4 a0 = __builtin_amdgcn_mfma_f32_16x16x32_bf16(*reinterpret_cast<const bf16x8*>(base +   0), bt, z, 0, 0, 0);
            f32x4 a1 = __builtin_amdgcn_mfma_f32_16x16x32_bf16(*reinterpret_cast<const bf16x8*>(base +  32), bt, z, 0, 0, 0);
            f32x4 a2 = __builtin_amdgcn_mfma_f32_16x16x32_bf16(*reinterpret_cast<const bf16x8*>(base +  64), bt, z, 0, 0, 0);
            f32x4 a3 = __builtin_amdgcn_mfma_f32_16x16x32_bf16(*reinterpret_cast<const bf16x8*>(base +  96), bt, z, 0, 0, 0);
            f32x4 a4 = __builtin_amdgcn_mfma_f32_16x16x32_bf16(*reinterpret_cast<const bf16x8*>(base + 128), bt, z, 0, 0, 0);
#pragma unroll
            for (int r = 0; r < 4; ++r) {
                int row = rf * 16 + (kg << 2) + r;
                float g = gT[rf][r] * INV_S32;
                float* po = out + (row0 + row) * DOUT + 320 + 5 * j;
                po[0] = a0[r] * g; po[1] = a1[r] * g; po[2] = a2[r] * g;
                po[3] = a3[r] * g; po[4] = a4[r] * g;
            }
        }
    }
}

extern "C" void kernel_launch(void* const* d_in, const int* in_sizes, int n_in,
                              void* d_out, int out_size, void* d_ws, size_t ws_size,
                              hipStream_t stream) {
    const float* x  = (const float*)d_in[0];
    const float* W0 = (const float*)d_in[1];
    const float* b0 = (const float*)d_in[2];
    const float* W1 = (const float*)d_in[3];
    const float* W2 = (const float*)d_in[4];
    float* out = (float*)d_out;
    dim3 grid(NROWS / M_TILE), block(256);
    if (ws_size >= WS_BYTES) {
        hipLaunchKernelGGL(prep_frags, dim3(WS_FRAGS), dim3(64), 0, stream, W0, W1, W2, (ushort*)d_ws);
        hipLaunchKernelGGL((percep_kernel<true>), grid, block, 0, stream,
                           x, W0, b0, W1, W2, out, (const ushort*)d_ws);
    } else {
        hipLaunchKernelGGL((percep_kernel<false>), grid, block, 0, stream,
                           x, W0, b0, W1, W2, out, (const ushort*)d_ws);
    }
}

// Round 5
// 222.180 us; speedup vs baseline: 1.2335x; 1.1199x over previous
//
#include <hip/hip_runtime.h>
#include <hip/hip_bf16.h>

#define NROWS   262144
#define DIN     480
#define DOUT    480

#define M_TILE  32
#define XSTR    488   // ushort stride; 976B/row, 16B-aligned rows, 2-way-bank b128 reads

#define CST_SILU 1.6765290f
#define CST_RELU 1.4142135623730951f
#define INV_S128 0.08838834764831845f
#define INV_S64  0.125f
#define INV_S32  0.17677669529663687f

// ws fragment layout (bf16x8 per lane, 1024B per fragment):
//   W0 tile t(0..13) kk(0..3) -> t*4+kk (0..55); W1 vu,kk -> 56+vu*2+kk; W2 tu -> 64+tu
#define WS_FRAGS 66
#define WS_BYTES (WS_FRAGS * 64 * 16)

typedef short bf16x8 __attribute__((ext_vector_type(8)));
typedef float f32x4  __attribute__((ext_vector_type(4)));

__device__ __forceinline__ ushort f2bf(float f) {
    unsigned u = __float_as_uint(f);
    u = (u + 0x7FFFu + ((u >> 16) & 1u)) >> 16;   // RNE
    return (ushort)u;
}

// packed f32 pair -> 2x bf16 in one u32 (compiler emits v_cvt_pk_bf16_f32)
__device__ __forceinline__ unsigned pk2(float a, float b) {
    __hip_bfloat162 h = __float22bfloat162_rn(float2{a, b});
    return *reinterpret_cast<unsigned*>(&h);
}

__device__ __forceinline__ bf16x8 load_b_frag(const float* __restrict__ W, int ldw,
                                              int kbase, int nbase, int lane) {
    int n  = nbase + (lane & 15);
    int k0 = kbase + ((lane >> 4) << 3);
    bf16x8 f;
#pragma unroll
    for (int e = 0; e < 8; ++e) f[e] = (short)f2bf(W[(k0 + e) * ldw + n]);
    return f;
}

__global__ __launch_bounds__(64) void prep_frags(
        const float* __restrict__ W0, const float* __restrict__ W1,
        const float* __restrict__ W2, ushort* __restrict__ ws) {
    const int b = blockIdx.x, lane = threadIdx.x;
    const int lr = lane & 15, kg = lane >> 4;
    const float* W; int ldw, n, k0;
    if (b < 56)      { W = W0; ldw = 224; n = (b >> 2) * 16 + lr; k0 = (b & 3) * 32 + (kg << 3); }
    else if (b < 64) { int t = b - 56; W = W1; ldw = 64; n = (t >> 1) * 16 + lr; k0 = (t & 1) * 32 + (kg << 3); }
    else             { W = W2; ldw = 32; n = (b - 64) * 16 + lr; k0 = (kg << 3); }
    bf16x8 f;
#pragma unroll
    for (int e = 0; e < 8; ++e) f[e] = (short)f2bf(W[(k0 + e) * ldw + n]);
    *reinterpret_cast<bf16x8*>(ws + (b * 64 + lane) * 8) = f;
}

template <bool PRE>
__global__ __launch_bounds__(256, 4) void percep_kernel(
        const float* __restrict__ x,  const float* __restrict__ W0,
        const float* __restrict__ bias0, const float* __restrict__ W1,
        const float* __restrict__ W2, float* __restrict__ out,
        const ushort* __restrict__ ws) {
    __shared__ __align__(16) ushort xs[M_TILE * XSTR];   // 31232 B

    const int tid  = threadIdx.x;
    const int lane = tid & 63;
    const int wid  = tid >> 6;
    const int lr   = lane & 15;
    const int kg   = lane >> 4;
    const int rf   = wid >> 1;      // row-panel: waves 0,1 -> rows 0-15; 2,3 -> 16-31
    const int half = wid & 1;       // column-half of the S/V/T work
    const int row0 = blockIdx.x * M_TILE;
    const bf16x8* F = reinterpret_cast<const bf16x8*>(ws);

    // ---------- stage all of x -> LDS bf16 (coalesced float4, packed cvt) ----------
    // x0: cols 0..127 straight ; x1[n,i,m]=x[n,128+3i+m] -> col 128+64m+i ;
    // x2[n,i,m]=x[n,320+5i+m] -> col 320+32m+i
#pragma unroll
    for (int it = 0; it < 4; ++it) {
        int idx = tid + it * 256;
        int row = idx >> 5, c4 = idx & 31;
        const float4 v = reinterpret_cast<const float4*>(x + (row0 + row) * DIN)[c4];
        uint2 o = { pk2(v.x, v.y), pk2(v.z, v.w) };
        *reinterpret_cast<uint2*>(&xs[row * XSTR + c4 * 4]) = o;
    }
#pragma unroll
    for (int it = 0; it < 2; ++it) {
        int idx = tid + it * 256;
        int row = idx >> 4, g = idx & 15;
        const float4* p = reinterpret_cast<const float4*>(x + (row0 + row) * DIN + 128 + 12 * g);
        float4 q0 = p[0], q1 = p[1], q2 = p[2];
        float v[12] = { q0.x, q0.y, q0.z, q0.w, q1.x, q1.y, q1.z, q1.w, q2.x, q2.y, q2.z, q2.w };
#pragma unroll
        for (int m = 0; m < 3; ++m) {
            uint2 o = { pk2(v[m], v[m + 3]), pk2(v[m + 6], v[m + 9]) };
            *reinterpret_cast<uint2*>(&xs[row * XSTR + 128 + 64 * m + 4 * g]) = o;
        }
    }
    {
        int row = tid >> 3, g = tid & 7;
        const float4* p = reinterpret_cast<const float4*>(x + (row0 + row) * DIN + 320 + 20 * g);
        float4 q0 = p[0], q1 = p[1], q2 = p[2], q3 = p[3], q4 = p[4];
        float v[20] = { q0.x, q0.y, q0.z, q0.w, q1.x, q1.y, q1.z, q1.w, q2.x, q2.y, q2.z, q2.w,
                        q3.x, q3.y, q3.z, q3.w, q4.x, q4.y, q4.z, q4.w };
#pragma unroll
        for (int m = 0; m < 5; ++m) {
            uint2 o = { pk2(v[m], v[m + 5]), pk2(v[m + 10], v[m + 15]) };
            *reinterpret_cast<uint2*>(&xs[row * XSTR + 320 + 32 * m + 4 * g]) = o;
        }
    }
    __syncthreads();   // the only barrier

    // ---------- A-frags for S (own row panel, from LDS) ----------
    bf16x8 aS[4];
#pragma unroll
    for (int kk = 0; kk < 4; ++kk)
        aS[kk] = *reinterpret_cast<const bf16x8*>(
            &xs[(rf * 16 + lr) * XSTR + kk * 32 + (kg << 3)]);

    // ---------- S phase: 3 gate tiles (registers, lane-matched) + 4 silu tiles ----------
    f32x4 gV0, gV1, gT;
    const int gt0 = half ? 10 : 8, gt1 = half ? 11 : 9, gt2 = half ? 13 : 12;

    auto s_acc = [&](int st) -> f32x4 {
        f32x4 acc = { 0.f, 0.f, 0.f, 0.f };
#pragma unroll
        for (int kk = 0; kk < 4; ++kk) {
            bf16x8 b = PRE ? F[(st * 4 + kk) * 64 + lane]
                           : load_b_frag(W0, 224, kk * 32, st * 16, lane);
            acc = __builtin_amdgcn_mfma_f32_16x16x32_bf16(aS[kk], b, acc, 0, 0, 0);
        }
        return acc;
    };
    auto gate_tile = [&](int st) -> f32x4 {
        f32x4 acc = s_acc(st);
        float bias = bias0[st * 16 + lr];
        f32x4 g;
#pragma unroll
        for (int r = 0; r < 4; ++r) {
            float s = acc[r] * INV_S128 + bias;
            g[r] = fmaxf(s, 0.f) * CST_RELU;
        }
        return g;
    };
    gV0 = gate_tile(gt0);
    gV1 = gate_tile(gt1);
    gT  = gate_tile(gt2);
#pragma unroll
    for (int t = 0; t < 4; ++t) {
        int st = half * 4 + t;
        f32x4 acc = s_acc(st);
        float bias = bias0[st * 16 + lr];
#pragma unroll
        for (int r = 0; r < 4; ++r) {
            float s = acc[r] * INV_S128 + bias;
            float val = CST_SILU * s * __builtin_amdgcn_rcpf(1.f + __expf(-s));
            out[(row0 + rf * 16 + (kg << 2) + r) * DOUT + st * 16 + lr] = val;
        }
    }

    // ---------- V: 2 j-tiles, A-frags shared across j-tiles ----------
    {
        bf16x8 aV[3][2];
#pragma unroll
        for (int m = 0; m < 3; ++m)
#pragma unroll
            for (int kk = 0; kk < 2; ++kk)
                aV[m][kk] = *reinterpret_cast<const bf16x8*>(
                    &xs[(rf * 16 + lr) * XSTR + 128 + m * 64 + kk * 32 + (kg << 3)]);
#pragma unroll
        for (int jt = 0; jt < 2; ++jt) {
            const int jtg = half * 2 + jt;
            f32x4 a0 = {0,0,0,0}, a1 = {0,0,0,0}, a2 = {0,0,0,0};
#pragma unroll
            for (int kk = 0; kk < 2; ++kk) {
                bf16x8 b = PRE ? F[(56 + jtg * 2 + kk) * 64 + lane]
                               : load_b_frag(W1, 64, kk * 32, jtg * 16, lane);
                a0 = __builtin_amdgcn_mfma_f32_16x16x32_bf16(aV[0][kk], b, a0, 0, 0, 0);
                a1 = __builtin_amdgcn_mfma_f32_16x16x32_bf16(aV[1][kk], b, a1, 0, 0, 0);
                a2 = __builtin_amdgcn_mfma_f32_16x16x32_bf16(aV[2][kk], b, a2, 0, 0, 0);
            }
            const f32x4& gv = jt ? gV1 : gV0;
            int j = jtg * 16 + lr;
#pragma unroll
            for (int r = 0; r < 4; ++r) {
                int row = rf * 16 + (kg << 2) + r;
                float g = gv[r] * INV_S64;
                float* po = out + (row0 + row) * DOUT + 128 + 3 * j;
                po[0] = a0[r] * g; po[1] = a1[r] * g; po[2] = a2[r] * g;
            }
        }
    }

    // ---------- T: 1 j-tile (K=32 -> single MFMA per m) ----------
    {
        bf16x8 bt = PRE ? F[(64 + half) * 64 + lane]
                        : load_b_frag(W2, 32, 0, half * 16, lane);
        const ushort* base = &xs[(rf * 16 + lr) * XSTR + 320 + (kg << 3)];
        f32x4 z = {0,0,0,0};
        f32x4 a0 = __builtin_amdgcn_mfma_f32_16x16x32_bf16(*reinterpret_cast<const bf16x8*>(base +   0), bt, z, 0, 0, 0);
        f32x4 a1 = __builtin_amdgcn_mfma_f32_16x16x32_bf16(*reinterpret_cast<const bf16x8*>(base +  32), bt, z, 0, 0, 0);
        f32x4 a2 = __builtin_amdgcn_mfma_f32_16x16x32_bf16(*reinterpret_cast<const bf16x8*>(base +  64), bt, z, 0, 0, 0);
        f32x4 a3 = __builtin_amdgcn_mfma_f32_16x16x32_bf16(*reinterpret_cast<const bf16x8*>(base +  96), bt, z, 0, 0, 0);
        f32x4 a4 = __builtin_amdgcn_mfma_f32_16x16x32_bf16(*reinterpret_cast<const bf16x8*>(base + 128), bt, z, 0, 0, 0);
        int j = half * 16 + lr;
#pragma unroll
        for (int r = 0; r < 4; ++r) {
            int row = rf * 16 + (kg << 2) + r;
            float g = gT[r] * INV_S32;
            float* po = out + (row0 + row) * DOUT + 320 + 5 * j;
            po[0] = a0[r] * g; po[1] = a1[r] * g; po[2] = a2[r] * g;
            po[3] = a3[r] * g; po[4] = a4[r] * g;
        }
    }
}

extern "C" void kernel_launch(void* const* d_in, const int* in_sizes, int n_in,
                              void* d_out, int out_size, void* d_ws, size_t ws_size,
                              hipStream_t stream) {
    const float* x  = (const float*)d_in[0];
    const float* W0 = (const float*)d_in[1];
    const float* b0 = (const float*)d_in[2];
    const float* W1 = (const float*)d_in[3];
    const float* W2 = (const float*)d_in[4];
    float* out = (float*)d_out;
    dim3 grid(NROWS / M_TILE), block(256);
    if (ws_size >= WS_BYTES) {
        hipLaunchKernelGGL(prep_frags, dim3(WS_FRAGS), dim3(64), 0, stream, W0, W1, W2, (ushort*)d_ws);
        hipLaunchKernelGGL((percep_kernel<true>), grid, block, 0, stream,
                           x, W0, b0, W1, W2, out, (const ushort*)d_ws);
    } else {
        hipLaunchKernelGGL((percep_kernel<false>), grid, block, 0, stream,
                           x, W0, b0, W1, W2, out, (const ushort*)d_ws);
    }
}